// Round 1
// baseline (394.432 us; speedup 1.0000x reference)
//
#include <hip/hip_runtime.h>
#include <math.h>

// GCN collapses to:
//   deg[c]  = 1 + #edges into c                      (edge pass 1, scalar atomics)
//   dinv    = 1/sqrt(deg)
//   s[c]    = sum_{e:col=c} dinv[row]*dinv[col]*x[row]    (edge pass 2)
//   wsum[r] = sum_{e:row=r} dinv[col]                      (edge pass 2)
//   s_tot[i] = s[i] + dinv[i]^2 * x[i]               (self loop)
//   w[i]     = dinv[i]*(wsum[i] + dinv[i])           (self loop)
//   total[k] = sum_i w[i] * relu(s_tot[i]*W1[k] + b1[k])
//   out[d]   = (total/N) @ W2[:,d] + b2[d]

__global__ void init_ws(float* __restrict__ dinv, float* __restrict__ s,
                        float* __restrict__ wsum, float* __restrict__ total,
                        int N, int H) {
    int i = blockIdx.x * blockDim.x + threadIdx.x;
    if (i < N) {
        dinv[i] = 1.0f;   // self-loop contribution to degree
        s[i]    = 0.0f;
        wsum[i] = 0.0f;
    }
    if (i < H) total[i] = 0.0f;
}

__global__ void deg_kernel(const int* __restrict__ col, float* __restrict__ deg, int E) {
    int idx = blockIdx.x * blockDim.x + threadIdx.x;
    int e = idx * 4;
    if (e + 3 < E) {
        int4 c = *reinterpret_cast<const int4*>(col + e);
        atomicAdd(&deg[c.x], 1.0f);
        atomicAdd(&deg[c.y], 1.0f);
        atomicAdd(&deg[c.z], 1.0f);
        atomicAdd(&deg[c.w], 1.0f);
    } else {
        for (; e < E; ++e) atomicAdd(&deg[col[e]], 1.0f);
    }
}

__global__ void rsqrt_kernel(float* __restrict__ deg, int N) {
    int i = blockIdx.x * blockDim.x + threadIdx.x;
    if (i < N) deg[i] = 1.0f / sqrtf(deg[i]);   // deg becomes dinv in place
}

__global__ void edge_kernel(const int* __restrict__ row, const int* __restrict__ col,
                            const float* __restrict__ x, const float* __restrict__ dinv,
                            float* __restrict__ s, float* __restrict__ wsum, int E) {
    int idx = blockIdx.x * blockDim.x + threadIdx.x;
    int e = idx * 4;
    if (e + 3 < E) {
        int4 r4 = *reinterpret_cast<const int4*>(row + e);
        int4 c4 = *reinterpret_cast<const int4*>(col + e);
        int rr[4] = {r4.x, r4.y, r4.z, r4.w};
        int cc[4] = {c4.x, c4.y, c4.z, c4.w};
#pragma unroll
        for (int j = 0; j < 4; ++j) {
            float dr = dinv[rr[j]];
            float dc = dinv[cc[j]];
            atomicAdd(&s[cc[j]], dr * dc * x[rr[j]]);
            atomicAdd(&wsum[rr[j]], dc);
        }
    } else {
        for (; e < E; ++e) {
            int r = row[e], c = col[e];
            float dr = dinv[r], dc = dinv[c];
            atomicAdd(&s[c], dr * dc * x[r]);
            atomicAdd(&wsum[r], dc);
        }
    }
}

// blockDim = 256 -> 2 node-groups of 128 threads; k = tid & 127
__global__ void node_reduce(const float* __restrict__ dinv, const float* __restrict__ s,
                            const float* __restrict__ wsum, const float* __restrict__ x,
                            const float* __restrict__ W1, const float* __restrict__ b1,
                            float* __restrict__ total, int N) {
    const int k = threadIdx.x & 127;
    const int group = threadIdx.x >> 7;            // 0..1
    const int groupsPerBlock = blockDim.x >> 7;    // 2
    float w1k = W1[k];
    float b1k = b1[k];
    float acc = 0.0f;
    for (int i = blockIdx.x * groupsPerBlock + group; i < N; i += gridDim.x * groupsPerBlock) {
        float di = dinv[i];
        float st = s[i] + di * di * x[i];          // + self-loop message
        float w  = di * (wsum[i] + di);            // outgoing-norm weight incl. self loop
        float h  = st * w1k + b1k;
        h = h > 0.0f ? h : 0.0f;                   // relu
        acc += w * h;
    }
    __shared__ float red[256];
    red[threadIdx.x] = acc;
    __syncthreads();
    if (threadIdx.x < 128) {
        atomicAdd(&total[k], red[threadIdx.x] + red[threadIdx.x + 128]);
    }
}

__global__ void final_matvec(const float* __restrict__ total, const float* __restrict__ W2,
                             const float* __restrict__ b2, float* __restrict__ out,
                             int H, int OUT, float invN) {
    __shared__ float t[128];
    if (threadIdx.x < H) t[threadIdx.x] = total[threadIdx.x] * invN;
    __syncthreads();
    int d = blockIdx.x * blockDim.x + threadIdx.x;
    if (d < OUT) {
        float acc = b2[d];
        for (int kk = 0; kk < H; ++kk) acc += t[kk] * W2[kk * OUT + d];
        out[d] = acc;
    }
}

extern "C" void kernel_launch(void* const* d_in, const int* in_sizes, int n_in,
                              void* d_out, int out_size, void* d_ws, size_t ws_size,
                              hipStream_t stream) {
    const float* x          = (const float*)d_in[0];
    const int*   edge_index = (const int*)  d_in[1];
    const float* W1         = (const float*)d_in[2];
    const float* b1         = (const float*)d_in[3];
    const float* W2         = (const float*)d_in[4];
    const float* b2         = (const float*)d_in[5];
    float* out = (float*)d_out;

    const int N   = in_sizes[0];      // 100000
    const int E   = in_sizes[1] / 2;  // 1600000
    const int H   = in_sizes[2];      // 128
    const int OUT = in_sizes[5];      // 400

    const int* row = edge_index;      // edge_index[0]
    const int* col = edge_index + E;  // edge_index[1]

    float* dinv  = (float*)d_ws;      // [N] (holds deg, then dinv)
    float* s     = dinv + N;          // [N]
    float* wsum  = s + N;             // [N]
    float* total = wsum + N;          // [H]

    init_ws<<<(N + 255) / 256, 256, 0, stream>>>(dinv, s, wsum, total, N, H);

    int nT = (E + 3) / 4;
    deg_kernel<<<(nT + 255) / 256, 256, 0, stream>>>(col, dinv, E);
    rsqrt_kernel<<<(N + 255) / 256, 256, 0, stream>>>(dinv, N);
    edge_kernel<<<(nT + 255) / 256, 256, 0, stream>>>(row, col, x, dinv, s, wsum, E);
    node_reduce<<<256, 256, 0, stream>>>(dinv, s, wsum, x, W1, b1, total, N);
    final_matvec<<<(OUT + 127) / 128, 128, 0, stream>>>(total, W2, b2, out, H, OUT,
                                                        1.0f / (float)N);
}

// Round 2
// 257.742 us; speedup vs baseline: 1.5303x; 1.5303x over previous
//
#include <hip/hip_runtime.h>
#include <math.h>

// GCN collapsed to scalar-per-node form (see R1). R2: replace per-edge global
// atomics (4.8M @ ~19G/s = atomic-path-bound) with chunked LDS histograms +
// non-atomic partial flush + tree reduce. Edge list (12.8MB) is L3-resident
// across chunk passes.
//
//   deg[c]  = 1 + hist(col)                         -> dinv = rsqrt(deg), u = dinv*x
//   s_raw[c]= sum_{e:col=c} u[row]                  -> sc[i] = dinv*s_raw + dinv^2*x
//   w_raw[r]= sum_{e:row=r} dinv[col]               -> w[i]  = dinv*(w_raw + dinv)
//   total[k]= sum_i w[i]*relu(sc[i]*W1[k]+b1[k])
//   out[d]  = total/N @ W2[:,d] + b2[d]

constexpr int CH_D  = 14336;  // deg chunk bins: 57344B LDS, R = ceil(N/CH_D)
constexpr int CH_SW = 7936;   // s&w chunk bins: 2*31744B = 63488B LDS

__global__ void deg_hist(const int* __restrict__ col, float* __restrict__ P,
                         int N, int E, int Eb, int B) {
    __shared__ float h[CH_D];
    const int r = blockIdx.x / B, b = blockIdx.x % B;
    const int lo = r * CH_D, hi = min(N, lo + CH_D), nb = hi - lo;
    for (int i = threadIdx.x; i < nb; i += blockDim.x) h[i] = 0.0f;
    __syncthreads();
    const int e0 = b * Eb, e1 = min(E, e0 + Eb);
    const int stride = blockDim.x * 4;
    const int J = (e1 - e0) / stride;
    for (int j = 0; j < J; ++j) {
        int e = e0 + j * stride + threadIdx.x * 4;
        int4 c = *reinterpret_cast<const int4*>(col + e);
        if (c.x >= lo && c.x < hi) atomicAdd(&h[c.x - lo], 1.0f);
        if (c.y >= lo && c.y < hi) atomicAdd(&h[c.y - lo], 1.0f);
        if (c.z >= lo && c.z < hi) atomicAdd(&h[c.z - lo], 1.0f);
        if (c.w >= lo && c.w < hi) atomicAdd(&h[c.w - lo], 1.0f);
    }
    for (int e = e0 + J * stride + threadIdx.x; e < e1; e += blockDim.x) {
        int c = col[e];
        if (c >= lo && c < hi) atomicAdd(&h[c - lo], 1.0f);
    }
    __syncthreads();
    for (int i = threadIdx.x; i < nb; i += blockDim.x)
        P[(size_t)b * N + lo + i] = h[i];
}

__global__ void reduce_deg(const float* __restrict__ P, const float* __restrict__ x,
                           float* __restrict__ dinv, float* __restrict__ u,
                           int N, int B) {
    int i = blockIdx.x * blockDim.x + threadIdx.x;
    if (i >= N) return;
    float d = 1.0f;  // self loop
    for (int b = 0; b < B; ++b) d += P[(size_t)b * N + i];
    float di = rsqrtf(d);
    dinv[i] = di;
    u[i] = di * x[i];
}

__global__ void sw_hist(const int* __restrict__ row, const int* __restrict__ col,
                        const float* __restrict__ u, const float* __restrict__ dinv,
                        float* __restrict__ Ps, float* __restrict__ Pw,
                        int N, int E, int Eb, int B) {
    __shared__ float hs[CH_SW];
    __shared__ float hw[CH_SW];
    const int r = blockIdx.x / B, b = blockIdx.x % B;
    const int lo = r * CH_SW, hi = min(N, lo + CH_SW), nb = hi - lo;
    for (int i = threadIdx.x; i < nb; i += blockDim.x) { hs[i] = 0.0f; hw[i] = 0.0f; }
    __syncthreads();
    const int e0 = b * Eb, e1 = min(E, e0 + Eb);
    const int stride = blockDim.x * 4;
    const int J = (e1 - e0) / stride;
    for (int j = 0; j < J; ++j) {
        int e = e0 + j * stride + threadIdx.x * 4;
        int4 r4 = *reinterpret_cast<const int4*>(row + e);
        int4 c4 = *reinterpret_cast<const int4*>(col + e);
        int rr[4] = {r4.x, r4.y, r4.z, r4.w};
        int cc[4] = {c4.x, c4.y, c4.z, c4.w};
#pragma unroll
        for (int t = 0; t < 4; ++t) {
            if (cc[t] >= lo && cc[t] < hi) atomicAdd(&hs[cc[t] - lo], u[rr[t]]);
            if (rr[t] >= lo && rr[t] < hi) atomicAdd(&hw[rr[t] - lo], dinv[cc[t]]);
        }
    }
    for (int e = e0 + J * stride + threadIdx.x; e < e1; e += blockDim.x) {
        int rr = row[e], cc = col[e];
        if (cc >= lo && cc < hi) atomicAdd(&hs[cc - lo], u[rr]);
        if (rr >= lo && rr < hi) atomicAdd(&hw[rr - lo], dinv[cc]);
    }
    __syncthreads();
    for (int i = threadIdx.x; i < nb; i += blockDim.x) {
        Ps[(size_t)b * N + lo + i] = hs[i];
        Pw[(size_t)b * N + lo + i] = hw[i];
    }
}

__global__ void reduce_sw(const float* __restrict__ Ps, const float* __restrict__ Pw,
                          const float* __restrict__ dinv, const float* __restrict__ x,
                          float* __restrict__ sc, float* __restrict__ w,
                          float* __restrict__ total, int N, int B, int H) {
    int i = blockIdx.x * blockDim.x + threadIdx.x;
    if (blockIdx.x == 0 && threadIdx.x < H) total[threadIdx.x] = 0.0f;
    if (i >= N) return;
    float sr = 0.0f, wr = 0.0f;
    for (int b = 0; b < B; ++b) {
        sr += Ps[(size_t)b * N + i];
        wr += Pw[(size_t)b * N + i];
    }
    float di = dinv[i];
    sc[i] = di * sr + di * di * x[i];   // + self-loop message
    w[i]  = di * (wr + di);             // outgoing weight incl. self loop
}

// blockDim = 256 -> 2 node-groups of 128 threads; k = tid & 127
__global__ void node_reduce(const float* __restrict__ sc, const float* __restrict__ w,
                            const float* __restrict__ W1, const float* __restrict__ b1,
                            float* __restrict__ total, int N) {
    const int k = threadIdx.x & 127;
    const int group = threadIdx.x >> 7;
    const int groupsPerBlock = blockDim.x >> 7;
    float w1k = W1[k];
    float b1k = b1[k];
    float acc = 0.0f;
    for (int i = blockIdx.x * groupsPerBlock + group; i < N; i += gridDim.x * groupsPerBlock) {
        float h = sc[i] * w1k + b1k;
        h = h > 0.0f ? h : 0.0f;
        acc += w[i] * h;
    }
    __shared__ float red[256];
    red[threadIdx.x] = acc;
    __syncthreads();
    if (threadIdx.x < 128)
        atomicAdd(&total[k], red[threadIdx.x] + red[threadIdx.x + 128]);
}

__global__ void final_matvec(const float* __restrict__ total, const float* __restrict__ W2,
                             const float* __restrict__ b2, float* __restrict__ out,
                             int H, int OUT, float invN) {
    __shared__ float t[128];
    if (threadIdx.x < H) t[threadIdx.x] = total[threadIdx.x] * invN;
    __syncthreads();
    int d = blockIdx.x * blockDim.x + threadIdx.x;
    if (d < OUT) {
        float acc = b2[d];
        for (int kk = 0; kk < H; ++kk) acc += t[kk] * W2[kk * OUT + d];
        out[d] = acc;
    }
}

extern "C" void kernel_launch(void* const* d_in, const int* in_sizes, int n_in,
                              void* d_out, int out_size, void* d_ws, size_t ws_size,
                              hipStream_t stream) {
    const float* x          = (const float*)d_in[0];
    const int*   edge_index = (const int*)  d_in[1];
    const float* W1         = (const float*)d_in[2];
    const float* b1         = (const float*)d_in[3];
    const float* W2         = (const float*)d_in[4];
    const float* b2         = (const float*)d_in[5];
    float* out = (float*)d_out;

    const int N   = in_sizes[0];      // 100000
    const int E   = in_sizes[1] / 2;  // 1600000
    const int H   = in_sizes[2];      // 128
    const int OUT = in_sizes[5];      // 400

    const int* row = edge_index;
    const int* col = edge_index + E;

    // workspace layout (floats)
    float* dinv  = (float*)d_ws;            // [N]
    float* u     = dinv + N;                // [N]
    float* sc    = u + N;                   // [N]
    float* w     = sc + N;                  // [N]
    float* total = w + N;                   // [H]
    float* P     = total + H;               // partials, aliased across phases

    const int B_D = 64;                     // deg edge partitions
    const int Eb_D = (E + B_D - 1) / B_D;
    const int R_D = (N + CH_D - 1) / CH_D;  // 7

    const int B_SW = 32;                    // s&w edge partitions
    const int Eb_SW = (E + B_SW - 1) / B_SW;
    const int R_SW = (N + CH_SW - 1) / CH_SW;  // 13

    float* Pdeg = P;                        // [B_D * N]   (25.6 MB)
    float* Ps   = P;                        // [B_SW * N]  (aliases Pdeg, sequential)
    float* Pw   = P + (size_t)B_SW * N;     // [B_SW * N]

    deg_hist<<<R_D * B_D, 256, 0, stream>>>(col, Pdeg, N, E, Eb_D, B_D);
    reduce_deg<<<(N + 255) / 256, 256, 0, stream>>>(Pdeg, x, dinv, u, N, B_D);
    sw_hist<<<R_SW * B_SW, 256, 0, stream>>>(row, col, u, dinv, Ps, Pw, N, E, Eb_SW, B_SW);
    reduce_sw<<<(N + 255) / 256, 256, 0, stream>>>(Ps, Pw, dinv, x, sc, w, total, N, B_SW, H);
    node_reduce<<<256, 256, 0, stream>>>(sc, w, W1, b1, total, N);
    final_matvec<<<(OUT + 127) / 128, 128, 0, stream>>>(total, W2, b2, out, H, OUT,
                                                        1.0f / (float)N);
}

// Round 3
// 227.329 us; speedup vs baseline: 1.7351x; 1.1338x over previous
//
#include <hip/hip_runtime.h>
#include <math.h>

// GCN collapsed to scalar-per-node form (R1), scatter via counting-sort (R3):
//   bucket = node >> 12  (25 buckets of 4096 nodes, N=100000 <= 32*4096)
//   SC[e'] = (col&4095)<<17 | row   sorted by col-bucket
//   SR[e'] = (row&4095)<<17 | col   sorted by row-bucket
//   deg-hist over SC (count), dinv=rsqrt(deg), u=dinv*x
//   s-hist over SC (gather u[row]), w-hist over SR (gather dinv[col])
//   total[k] = sum_i w[i]*relu(sc[i]*W1[k]+b1[k]);  out = total/N @ W2 + b2

constexpr int BKT_BITS = 12;
constexpr int BKT_SIZE = 1 << BKT_BITS;   // 4096
constexpr int NBMAX    = 32;
constexpr int SLICES   = 10;
constexpr int EPT      = 8;               // edges per thread in scatter

__global__ void init_misc(int* __restrict__ ints, float* __restrict__ total, int H) {
    int t = threadIdx.x;
    if (t < 64) ints[t] = 0;              // cntC[32], cntR[32]
    if (t < H) total[t] = 0.0f;
}

__global__ void count_buckets(const int* __restrict__ row, const int* __restrict__ col,
                              int* __restrict__ cntC, int* __restrict__ cntR, int E) {
    __shared__ int hC[NBMAX], hR[NBMAX];
    if (threadIdx.x < NBMAX) { hC[threadIdx.x] = 0; hR[threadIdx.x] = 0; }
    __syncthreads();
    const int stride = gridDim.x * blockDim.x;
    const int idx = blockIdx.x * blockDim.x + threadIdx.x;
    const int nv = E >> 2;
    for (int q = idx; q < nv; q += stride) {
        int4 c = reinterpret_cast<const int4*>(col)[q];
        int4 r = reinterpret_cast<const int4*>(row)[q];
        atomicAdd(&hC[c.x >> BKT_BITS], 1); atomicAdd(&hC[c.y >> BKT_BITS], 1);
        atomicAdd(&hC[c.z >> BKT_BITS], 1); atomicAdd(&hC[c.w >> BKT_BITS], 1);
        atomicAdd(&hR[r.x >> BKT_BITS], 1); atomicAdd(&hR[r.y >> BKT_BITS], 1);
        atomicAdd(&hR[r.z >> BKT_BITS], 1); atomicAdd(&hR[r.w >> BKT_BITS], 1);
    }
    for (int e = (nv << 2) + idx; e < E; e += stride) {
        atomicAdd(&hC[col[e] >> BKT_BITS], 1);
        atomicAdd(&hR[row[e] >> BKT_BITS], 1);
    }
    __syncthreads();
    if (threadIdx.x < NBMAX) {
        atomicAdd(&cntC[threadIdx.x], hC[threadIdx.x]);
        atomicAdd(&cntR[threadIdx.x], hR[threadIdx.x]);
    }
}

__global__ void scan_offsets(const int* __restrict__ cntC, const int* __restrict__ cntR,
                             int* __restrict__ offC, int* __restrict__ offR,
                             int* __restrict__ curC, int* __restrict__ curR) {
    if (threadIdx.x == 0) {
        int a = 0;
        for (int b = 0; b < NBMAX; ++b) { offC[b] = a; curC[b] = a; a += cntC[b]; }
        offC[NBMAX] = a;
        a = 0;
        for (int b = 0; b < NBMAX; ++b) { offR[b] = a; curR[b] = a; a += cntR[b]; }
        offR[NBMAX] = a;
    }
}

__global__ void scatter_edges(const int* __restrict__ row, const int* __restrict__ col,
                              int* __restrict__ SC, int* __restrict__ SR,
                              int* __restrict__ curC, int* __restrict__ curR, int E) {
    __shared__ int hC[NBMAX], hR[NBMAX], bC[NBMAX], bR[NBMAX];
    const int TILE = blockDim.x * EPT;
    const int nTiles = (E + TILE - 1) / TILE;
    for (int t = blockIdx.x; t < nTiles; t += gridDim.x) {
        const int myBase = t * TILE + threadIdx.x * EPT;
        int r[EPT], c[EPT];
        if (myBase + EPT <= E) {
            int4 r0 = *reinterpret_cast<const int4*>(row + myBase);
            int4 r1 = *reinterpret_cast<const int4*>(row + myBase + 4);
            int4 c0 = *reinterpret_cast<const int4*>(col + myBase);
            int4 c1 = *reinterpret_cast<const int4*>(col + myBase + 4);
            r[0]=r0.x; r[1]=r0.y; r[2]=r0.z; r[3]=r0.w;
            r[4]=r1.x; r[5]=r1.y; r[6]=r1.z; r[7]=r1.w;
            c[0]=c0.x; c[1]=c0.y; c[2]=c0.z; c[3]=c0.w;
            c[4]=c1.x; c[5]=c1.y; c[6]=c1.z; c[7]=c1.w;
        } else {
#pragma unroll
            for (int j = 0; j < EPT; ++j) {
                int e = myBase + j;
                r[j] = (e < E) ? row[e] : -1;
                c[j] = (e < E) ? col[e] : -1;
            }
        }
        if (threadIdx.x < NBMAX) { hC[threadIdx.x] = 0; hR[threadIdx.x] = 0; }
        __syncthreads();
#pragma unroll
        for (int j = 0; j < EPT; ++j) {
            if (r[j] >= 0) {
                atomicAdd(&hC[c[j] >> BKT_BITS], 1);
                atomicAdd(&hR[r[j] >> BKT_BITS], 1);
            }
        }
        __syncthreads();
        if (threadIdx.x < NBMAX) {
            bC[threadIdx.x] = atomicAdd(&curC[threadIdx.x], hC[threadIdx.x]);
            hC[threadIdx.x] = 0;
            bR[threadIdx.x] = atomicAdd(&curR[threadIdx.x], hR[threadIdx.x]);
            hR[threadIdx.x] = 0;
        }
        __syncthreads();
#pragma unroll
        for (int j = 0; j < EPT; ++j) {
            if (r[j] >= 0) {
                int kb = c[j] >> BKT_BITS;
                int rk = atomicAdd(&hC[kb], 1);
                SC[bC[kb] + rk] = ((c[j] & (BKT_SIZE - 1)) << 17) | r[j];
                int kb2 = r[j] >> BKT_BITS;
                int rk2 = atomicAdd(&hR[kb2], 1);
                SR[bR[kb2] + rk2] = ((r[j] & (BKT_SIZE - 1)) << 17) | c[j];
            }
        }
        __syncthreads();
    }
}

__global__ void hist_deg(const int* __restrict__ SC, const int* __restrict__ off,
                         float* __restrict__ P, int stride) {
    __shared__ float bins[BKT_SIZE];
    const int b = blockIdx.x / SLICES, s = blockIdx.x % SLICES;
    const int e0 = off[b], len = off[b + 1] - e0;
    const int lo = e0 + (int)((long long)len * s / SLICES);
    const int hi = e0 + (int)((long long)len * (s + 1) / SLICES);
    for (int i = threadIdx.x; i < BKT_SIZE; i += blockDim.x) bins[i] = 0.0f;
    __syncthreads();
    for (int e = lo + threadIdx.x; e < hi; e += blockDim.x)
        atomicAdd(&bins[SC[e] >> 17], 1.0f);
    __syncthreads();
    float* dst = P + (size_t)s * stride + b * BKT_SIZE;
    for (int i = threadIdx.x; i < BKT_SIZE; i += blockDim.x) dst[i] = bins[i];
}

__global__ void finalize_deg(const float* __restrict__ Pd, const float* __restrict__ x,
                             float* __restrict__ dinv, float* __restrict__ u,
                             int N, int stride) {
    int i = blockIdx.x * blockDim.x + threadIdx.x;
    if (i >= N) return;
    float d = 1.0f;  // self loop
    for (int s = 0; s < SLICES; ++s) d += Pd[(size_t)s * stride + i];
    float di = rsqrtf(d);
    dinv[i] = di;
    u[i] = di * x[i];
}

__global__ void hist_gather(const int* __restrict__ S, const int* __restrict__ off,
                            const float* __restrict__ val, float* __restrict__ P,
                            int stride) {
    __shared__ float bins[BKT_SIZE];
    const int b = blockIdx.x / SLICES, s = blockIdx.x % SLICES;
    const int e0 = off[b], len = off[b + 1] - e0;
    const int lo = e0 + (int)((long long)len * s / SLICES);
    const int hi = e0 + (int)((long long)len * (s + 1) / SLICES);
    for (int i = threadIdx.x; i < BKT_SIZE; i += blockDim.x) bins[i] = 0.0f;
    __syncthreads();
    for (int e = lo + threadIdx.x; e < hi; e += blockDim.x) {
        int v = S[e];
        atomicAdd(&bins[v >> 17], val[v & 0x1FFFF]);
    }
    __syncthreads();
    float* dst = P + (size_t)s * stride + b * BKT_SIZE;
    for (int i = threadIdx.x; i < BKT_SIZE; i += blockDim.x) dst[i] = bins[i];
}

__global__ void finalize_sw(const float* __restrict__ Ps, const float* __restrict__ Pw,
                            const float* __restrict__ dinv, const float* __restrict__ x,
                            float* __restrict__ sc, float* __restrict__ w,
                            int N, int stride) {
    int i = blockIdx.x * blockDim.x + threadIdx.x;
    if (i >= N) return;
    float sr = 0.0f, wr = 0.0f;
    for (int s = 0; s < SLICES; ++s) {
        sr += Ps[(size_t)s * stride + i];
        wr += Pw[(size_t)s * stride + i];
    }
    float di = dinv[i];
    sc[i] = di * sr + di * di * x[i];
    w[i]  = di * (wr + di);
}

__global__ void node_reduce(const float* __restrict__ sc, const float* __restrict__ w,
                            const float* __restrict__ W1, const float* __restrict__ b1,
                            float* __restrict__ total, int N) {
    const int k = threadIdx.x & 127;
    const int group = threadIdx.x >> 7;
    const int groupsPerBlock = blockDim.x >> 7;
    float w1k = W1[k];
    float b1k = b1[k];
    float acc = 0.0f;
    for (int i = blockIdx.x * groupsPerBlock + group; i < N; i += gridDim.x * groupsPerBlock) {
        float h = sc[i] * w1k + b1k;
        h = h > 0.0f ? h : 0.0f;
        acc += w[i] * h;
    }
    __shared__ float red[256];
    red[threadIdx.x] = acc;
    __syncthreads();
    if (threadIdx.x < 128)
        atomicAdd(&total[k], red[threadIdx.x] + red[threadIdx.x + 128]);
}

__global__ void final_matvec(const float* __restrict__ total, const float* __restrict__ W2,
                             const float* __restrict__ b2, float* __restrict__ out,
                             int H, int OUT, float invN) {
    __shared__ float t[128];
    if (threadIdx.x < H) t[threadIdx.x] = total[threadIdx.x] * invN;
    __syncthreads();
    int d = blockIdx.x * blockDim.x + threadIdx.x;
    if (d < OUT) {
        float acc = b2[d];
        for (int kk = 0; kk < H; ++kk) acc += t[kk] * W2[kk * OUT + d];
        out[d] = acc;
    }
}

extern "C" void kernel_launch(void* const* d_in, const int* in_sizes, int n_in,
                              void* d_out, int out_size, void* d_ws, size_t ws_size,
                              hipStream_t stream) {
    const float* x          = (const float*)d_in[0];
    const int*   edge_index = (const int*)  d_in[1];
    const float* W1         = (const float*)d_in[2];
    const float* b1         = (const float*)d_in[3];
    const float* W2         = (const float*)d_in[4];
    const float* b2         = (const float*)d_in[5];
    float* out = (float*)d_out;

    const int N   = in_sizes[0];      // 100000
    const int E   = in_sizes[1] / 2;  // 1600000
    const int H   = in_sizes[2];      // 128
    const int OUT = in_sizes[5];      // 400

    const int* row = edge_index;
    const int* col = edge_index + E;

    const int NB = (N + BKT_SIZE - 1) >> BKT_BITS;   // 25
    const int stride = NB * BKT_SIZE;                // 102400 (>= N)

    // workspace layout
    char* p = (char*)d_ws;
    float* dinv  = (float*)p; p += (size_t)N * 4;
    float* u     = (float*)p; p += (size_t)N * 4;
    float* sc    = (float*)p; p += (size_t)N * 4;
    float* w     = (float*)p; p += (size_t)N * 4;
    float* total = (float*)p; p += 512;
    int*   ints  = (int*)p;   p += 1024;             // cnt/off/cur arrays
    int*   SC    = (int*)p;   p += (size_t)E * 4;
    int*   SR    = (int*)p;   p += (size_t)E * 4;
    float* P1    = (float*)p; p += (size_t)SLICES * stride * 4;  // Pd then Ps
    float* P2    = (float*)p;                                    // Pw

    int* cntC = ints;        int* cntR = ints + 32;
    int* offC = ints + 64;   int* offR = ints + 97;   // 33 each
    int* curC = ints + 130;  int* curR = ints + 162;

    init_misc<<<1, 256, 0, stream>>>(ints, total, H);
    count_buckets<<<512, 256, 0, stream>>>(row, col, cntC, cntR, E);
    scan_offsets<<<1, 64, 0, stream>>>(cntC, cntR, offC, offR, curC, curR);
    scatter_edges<<<512, 256, 0, stream>>>(row, col, SC, SR, curC, curR, E);
    hist_deg<<<NB * SLICES, 256, 0, stream>>>(SC, offC, P1, stride);
    finalize_deg<<<(N + 255) / 256, 256, 0, stream>>>(P1, x, dinv, u, N, stride);
    hist_gather<<<NB * SLICES, 256, 0, stream>>>(SC, offC, u, P1, stride);     // Ps
    hist_gather<<<NB * SLICES, 256, 0, stream>>>(SR, offR, dinv, P2, stride);  // Pw
    finalize_sw<<<(N + 255) / 256, 256, 0, stream>>>(P1, P2, dinv, x, sc, w, N, stride);
    node_reduce<<<256, 256, 0, stream>>>(sc, w, W1, b1, total, N);
    final_matvec<<<(OUT + 127) / 128, 128, 0, stream>>>(total, W2, b2, out, H, OUT,
                                                        1.0f / (float)N);
}